// Round 2
// baseline (231.114 us; speedup 1.0000x reference)
//
#include <hip/hip_runtime.h>
#include <hip/hip_bf16.h>

// BMSampling: out[b,c,k,j,i] = sum_t X[b,c,t] * w[t,k,j,i]
// where w has <=2 nonzeros per (k,j,i): linear-interp taps at floor/ceil(xp).
// Strategy: precompute per-(k,j,i) taps (fp64, bit-matching numpy) into
// __device__ tables, then a store-bound gather kernel writes 655 MB output.

#define T_DIM 100
#define N_SMP 32
#define D_PROP 100
#define NKJI (N_SMP * D_PROP * T_DIM)   // 320000 table entries
#define BC_TOTAL 512                    // B*C = 4*128
#define NF4_PER_BC (NKJI / 4)           // 80000 float4 per (b,c) row

// Tap tables, rebuilt every kernel_launch (deterministic).
__device__ __align__(16) float2        g_wtab[NKJI];   // (wl, wr)
__device__ __align__(16) unsigned short g_ltab[NKJI];  // left | (right<<8)

__global__ __launch_bounds__(256) void bms_build_table() {
    // CRITICAL: numpy computes xp = xmin_ext + k*bin_size as separate fp64
    // mul + add (two roundings). hipcc's default -ffp-contract=fast would
    // fuse this into one FMA, flipping floor/ceil at exact-integer xp
    // (where the reference weight is 2.0). Disable contraction here.
    #pragma clang fp contract(off)

    int e = blockIdx.x * blockDim.x + threadIdx.x;
    if (e >= NKJI) return;
    int i = e % T_DIM;
    int j = (e / T_DIM) % D_PROP;
    int k = e / (T_DIM * D_PROP);

    float wl = 0.0f, wr = 0.0f;
    int left = 0, right = 0;

    // python: for i in range(T-1): for j in range(min(T-1-i, D))  ->  i+j <= 98
    if (i + j <= T_DIM - 2) {
        int length = (j + 1) - i;                       // xmax - xmin (can be negative)
        double xmin_ext = (double)i - (double)length * 0.5;
        double xmax_ext = (double)(j + 1) + (double)length * 0.5;
        double bin_size = (xmax_ext - xmin_ext) / (double)(N_SMP - 1);
        double kb = (double)k * bin_size;               // separate mul...
        double xp = xmin_ext + kb;                      // ...then add (no FMA)
        if (xp >= 0.0 && xp <= (double)(T_DIM - 1)) {
            double fl = floor(xp);
            double cl = ceil(xp);
            left  = (int)fl;
            right = (int)cl;
            wl = (float)(1.0 - (xp - fl));
            wr = (float)(1.0 - (cl - xp));
        }
    }
    g_wtab[e] = make_float2(wl, wr);
    g_ltab[e] = (unsigned short)(left | (right << 8));
}

__global__ __launch_bounds__(256) void bms_main(const float* __restrict__ X,
                                                float4* __restrict__ out) {
    __shared__ float xs[T_DIM];
    const int bc  = blockIdx.y;
    const int tid = threadIdx.x;
    if (tid < T_DIM) xs[tid] = X[bc * T_DIM + tid];
    __syncthreads();

    const int t4 = blockIdx.x * blockDim.x + tid;   // float4 index within this bc row
    if (t4 >= NF4_PER_BC) return;

    const float4*  wtab4 = reinterpret_cast<const float4*>(g_wtab);
    const ushort4* ltab4 = reinterpret_cast<const ushort4*>(g_ltab);

    float4 wA = wtab4[2 * t4];      // (wl0, wr0, wl1, wr1)
    float4 wB = wtab4[2 * t4 + 1];  // (wl2, wr2, wl3, wr3)
    ushort4 lv = ltab4[t4];

    float4 o;
    o.x = xs[lv.x & 0xFF] * wA.x + xs[lv.x >> 8] * wA.y;
    o.y = xs[lv.y & 0xFF] * wA.z + xs[lv.y >> 8] * wA.w;
    o.z = xs[lv.z & 0xFF] * wB.x + xs[lv.z >> 8] * wB.y;
    o.w = xs[lv.w & 0xFF] * wB.z + xs[lv.w >> 8] * wB.w;

    out[(size_t)bc * NF4_PER_BC + t4] = o;
}

extern "C" void kernel_launch(void* const* d_in, const int* in_sizes, int n_in,
                              void* d_out, int out_size, void* d_ws, size_t ws_size,
                              hipStream_t stream) {
    const float* X = (const float*)d_in[0];   // [4,128,100] fp32
    float4* out = (float4*)d_out;             // [4,128,32,100,100] fp32

    // Kernel 1: build tap tables (320000 entries).
    {
        dim3 grid((NKJI + 255) / 256);
        bms_build_table<<<grid, 256, 0, stream>>>();
    }
    // Kernel 2: store-bound gather. grid.y = bc (512 rows), grid.x covers 80000 float4.
    {
        dim3 grid((NF4_PER_BC + 255) / 256, BC_TOTAL);
        bms_main<<<grid, 256, 0, stream>>>(X, out);
    }
}

// Round 3
// 129.701 us; speedup vs baseline: 1.7819x; 1.7819x over previous
//
#include <hip/hip_runtime.h>
#include <hip/hip_bf16.h>

// BMSampling: out[b,c,k,j,i] = sum_t X[b,c,t] * w[t,k,j,i]
// w has <=2 nonzeros per (k,j,i): linear-interp taps at floor/ceil(xp).
// Kernel 1 precomputes taps (fp64, bit-matching numpy, fp-contract OFF).
// Kernel 2 is store-bound: taps cached in REGISTERS, looped over bc chunk,
// nontemporal float4 stores (655 MB output = the roofline).

#define T_DIM 100
#define N_SMP 32
#define D_PROP 100
#define NKJI (N_SMP * D_PROP * T_DIM)   // 320000 table entries
#define BC_TOTAL 512                    // B*C = 4*128
#define NF4_PER_BC (NKJI / 4)           // 80000 float4 per (b,c) row
#define BC_CHUNK 32                     // bc rows per block (LDS: 12.8 KB)

typedef float f4 __attribute__((ext_vector_type(4)));

// Tap tables, rebuilt every kernel_launch (deterministic).
__device__ __align__(16) float2         g_wtab[NKJI];  // (wl, wr)
__device__ __align__(16) unsigned short g_ltab[NKJI];  // left | (right<<8)

__global__ __launch_bounds__(256) void bms_build_table() {
    // numpy computes xp = xmin_ext + k*bin_size as separate fp64 mul + add.
    // hipcc's default -ffp-contract=fast would fuse into one FMA, flipping
    // floor/ceil at exact-integer xp (where reference weight = 2.0).
    #pragma clang fp contract(off)

    int e = blockIdx.x * blockDim.x + threadIdx.x;
    if (e >= NKJI) return;
    int i = e % T_DIM;
    int j = (e / T_DIM) % D_PROP;
    int k = e / (T_DIM * D_PROP);

    float wl = 0.0f, wr = 0.0f;
    int left = 0, right = 0;

    if (i + j <= T_DIM - 2) {                           // i+j <= 98
        int length = (j + 1) - i;                       // can be negative
        double xmin_ext = (double)i - (double)length * 0.5;
        double xmax_ext = (double)(j + 1) + (double)length * 0.5;
        double bin_size = (xmax_ext - xmin_ext) / (double)(N_SMP - 1);
        double kb = (double)k * bin_size;               // separate mul...
        double xp = xmin_ext + kb;                      // ...then add (no FMA)
        if (xp >= 0.0 && xp <= (double)(T_DIM - 1)) {
            double fl = floor(xp);
            double cl = ceil(xp);
            left  = (int)fl;
            right = (int)cl;
            wl = (float)(1.0 - (xp - fl));
            wr = (float)(1.0 - (cl - xp));
        }
    }
    g_wtab[e] = make_float2(wl, wr);
    g_ltab[e] = (unsigned short)(left | (right << 8));
}

__global__ __launch_bounds__(256) void bms_main(const float* __restrict__ X,
                                                f4* __restrict__ out) {
    __shared__ float xs[BC_CHUNK * T_DIM];              // 12.8 KB
    const int bc0 = blockIdx.y * BC_CHUNK;

    // Stage X chunk (contiguous 12.8 KB, 16B-aligned: bc0*400 % 16 == 0).
    {
        const f4* src = reinterpret_cast<const f4*>(X + bc0 * T_DIM);
        f4* dst = reinterpret_cast<f4*>(xs);
        for (int idx = threadIdx.x; idx < (BC_CHUNK * T_DIM) / 4; idx += 256)
            dst[idx] = src[idx];
    }
    __syncthreads();

    const int t4 = blockIdx.x * blockDim.x + threadIdx.x;
    if (t4 >= NF4_PER_BC) return;

    // Tap entry -> registers, ONCE per thread (read 16x total vs 512x before).
    const f4*      wtab4 = reinterpret_cast<const f4*>(g_wtab);
    const ushort4* ltab4 = reinterpret_cast<const ushort4*>(g_ltab);
    const f4 wA = wtab4[2 * t4];        // (wl0, wr0, wl1, wr1)
    const f4 wB = wtab4[2 * t4 + 1];    // (wl2, wr2, wl3, wr3)
    const ushort4 lv = ltab4[t4];
    const int l0 = lv.x & 0xFF, r0 = lv.x >> 8;
    const int l1 = lv.y & 0xFF, r1 = lv.y >> 8;
    const int l2 = lv.z & 0xFF, r2 = lv.z >> 8;
    const int l3 = lv.w & 0xFF, r3 = lv.w >> 8;

    f4* obase = out + (size_t)bc0 * NF4_PER_BC + t4;
    #pragma unroll 4
    for (int b = 0; b < BC_CHUNK; ++b) {
        const float* x = xs + b * T_DIM;
        f4 o;
        o.x = x[l0] * wA.x + x[r0] * wA.y;
        o.y = x[l1] * wA.z + x[r1] * wA.w;
        o.z = x[l2] * wB.x + x[r2] * wB.y;
        o.w = x[l3] * wB.z + x[r3] * wB.w;
        // Nontemporal: don't let the 655 MB write stream thrash L2.
        __builtin_nontemporal_store(o, obase + (size_t)b * NF4_PER_BC);
    }
}

extern "C" void kernel_launch(void* const* d_in, const int* in_sizes, int n_in,
                              void* d_out, int out_size, void* d_ws, size_t ws_size,
                              hipStream_t stream) {
    const float* X = (const float*)d_in[0];   // [4,128,100] fp32
    f4* out = (f4*)d_out;                     // [4,128,32,100,100] fp32

    // Kernel 1: build tap tables (320000 entries).
    {
        dim3 grid((NKJI + 255) / 256);
        bms_build_table<<<grid, 256, 0, stream>>>();
    }
    // Kernel 2: store-bound gather. grid.x covers 80000 float4,
    // grid.y = 16 chunks of 32 bc rows.
    {
        dim3 grid((NF4_PER_BC + 255) / 256, BC_TOTAL / BC_CHUNK);
        bms_main<<<grid, 256, 0, stream>>>(X, out);
    }
}

// Round 4
// 123.168 us; speedup vs baseline: 1.8764x; 1.0530x over previous
//
#include <hip/hip_runtime.h>
#include <hip/hip_bf16.h>

// BMSampling: out[bc, k, j, i] = X[bc, left]*wl + X[bc, right]*wr
// (the [100, 320000] weight matrix is analytically sparse: <=2 linear-interp
// taps per column). Single fused kernel: each thread owns ONE (k,j,i) column,
// computes its fp64 taps inline (bit-matching numpy, fp-contract OFF), then
// streams 32 bc rows with nontemporal dword stores.
//
// Why one output per thread (vs float4): adjacent lanes then differ by
// Delta-i = 1, and the tap index slope dl/di in [-0.5, 1.5] keeps the
// cross-lane LDS gather stride <= ~1.5 floats -> >=21 banks touched ->
// <=2-3-way conflicts (free), vs 4-8-way at Delta-i = 4. Stores remain
// perfectly coalesced (64 consecutive dwords per wave-instr).

#define T_DIM 100
#define N_SMP 32
#define D_PROP 100
#define NKJI (N_SMP * D_PROP * T_DIM)   // 320000 columns
#define BC_TOTAL 512                    // B*C = 4*128
#define BC_CHUNK 32                     // bc rows per block (LDS: 12.8 KB)

typedef float f4 __attribute__((ext_vector_type(4)));

__global__ __launch_bounds__(256) void bms_fused(const float* __restrict__ X,
                                                 float* __restrict__ out) {
    __shared__ float xs[BC_CHUNK * T_DIM];              // 12.8 KB
    const int bc0 = blockIdx.y * BC_CHUNK;

    // Stage X chunk (contiguous, 16B-aligned: bc0*400B % 16 == 0).
    {
        const f4* src = reinterpret_cast<const f4*>(X + bc0 * T_DIM);
        f4* dst = reinterpret_cast<f4*>(xs);
        for (int idx = threadIdx.x; idx < (BC_CHUNK * T_DIM) / 4; idx += 256)
            dst[idx] = src[idx];
    }
    __syncthreads();

    // grid.x * 256 == NKJI exactly (1250 * 256 = 320000): no bounds guard.
    const int e = blockIdx.x * 256 + threadIdx.x;
    const int i = e % T_DIM;
    const int j = (e / T_DIM) % D_PROP;
    const int k = e / (T_DIM * D_PROP);

    float wl = 0.0f, wr = 0.0f;
    int left = 0, right = 0;
    {
        // numpy computes xp = xmin_ext + k*bin_size as separate fp64 mul+add.
        // hipcc's default -ffp-contract=fast would fuse into one FMA, flipping
        // floor/ceil at exact-integer xp (where the reference weight is 2.0).
        #pragma clang fp contract(off)
        if (i + j <= T_DIM - 2) {                       // i+j <= 98
            int length = (j + 1) - i;                   // can be negative
            double xmin_ext = (double)i - (double)length * 0.5;
            double xmax_ext = (double)(j + 1) + (double)length * 0.5;
            double bin_size = (xmax_ext - xmin_ext) / (double)(N_SMP - 1);
            double kb = (double)k * bin_size;           // separate mul...
            double xp = xmin_ext + kb;                  // ...then add (no FMA)
            if (xp >= 0.0 && xp <= (double)(T_DIM - 1)) {
                double fl = floor(xp);
                double cl = ceil(xp);
                left  = (int)fl;
                right = (int)cl;
                wl = (float)(1.0 - (xp - fl));
                wr = (float)(1.0 - (cl - xp));
            }
        }
    }

    const float* x = xs;
    float* o = out + (size_t)bc0 * NKJI + e;
    #pragma unroll 8
    for (int b = 0; b < BC_CHUNK; ++b) {
        float v = x[left] * wl + x[right] * wr;
        // Nontemporal: keep the 655 MB write stream out of L2.
        __builtin_nontemporal_store(v, o);
        x += T_DIM;
        o += NKJI;
    }
}

extern "C" void kernel_launch(void* const* d_in, const int* in_sizes, int n_in,
                              void* d_out, int out_size, void* d_ws, size_t ws_size,
                              hipStream_t stream) {
    const float* X = (const float*)d_in[0];   // [4,128,100] fp32
    float* out = (float*)d_out;               // [4,128,32,100,100] fp32

    dim3 grid(NKJI / 256, BC_TOTAL / BC_CHUNK);   // (1250, 16)
    bms_fused<<<grid, 256, 0, stream>>>(X, out);
}

// Round 5
// 122.809 us; speedup vs baseline: 1.8819x; 1.0029x over previous
//
#include <hip/hip_runtime.h>
#include <hip/hip_bf16.h>

// BMSampling: out[bc, e] = X[bc, left(e)]*wl(e) + X[bc, right(e)]*wr(e)
// (the [100, 320000] weight matrix is analytically sparse: <=2 linear-interp
// taps per column e=(k,j,i)). Single fused kernel: each thread owns FOUR
// consecutive e (one float4 store), computes the 4 fp64 tap chains inline
// (bit-matching numpy, fp-contract OFF), then streams 32 bc rows.
//
// float4-per-thread => 1 KB contiguous per wave store instr, 4 KB contiguous
// per block per bc-iteration (vs 1 KB scalar) — targets HBM write efficiency.
// The LDS gather stride grows to ~6 floats/lane (4-way bank conflict, 1.58x)
// but LDS is a separate pipe and stays under the store roofline.

#define T_DIM 100
#define N_SMP 32
#define D_PROP 100
#define NKJI (N_SMP * D_PROP * T_DIM)   // 320000 columns
#define NF4 (NKJI / 4)                  // 80000 float4 per bc row
#define BC_TOTAL 512                    // B*C = 4*128
#define BC_CHUNK 32                     // bc rows per block (LDS: 12.8 KB)

typedef float f4 __attribute__((ext_vector_type(4)));

__global__ __launch_bounds__(256) void bms_fused(const float* __restrict__ X,
                                                 f4* __restrict__ out) {
    __shared__ float xs[BC_CHUNK * T_DIM];              // 12.8 KB
    const int bc0 = blockIdx.y * BC_CHUNK;

    // Stage X chunk (contiguous, 16B-aligned: bc0*400B % 16 == 0).
    {
        const f4* src = reinterpret_cast<const f4*>(X + bc0 * T_DIM);
        f4* dst = reinterpret_cast<f4*>(xs);
        for (int idx = threadIdx.x; idx < (BC_CHUNK * T_DIM) / 4; idx += 256)
            dst[idx] = src[idx];
    }
    __syncthreads();

    const int t4 = blockIdx.x * 256 + threadIdx.x;      // float4 index
    const bool active = (t4 < NF4);

    // Per-element taps for the 4 consecutive e values (4 independent chains;
    // they can straddle a j boundary, so each recomputes i,j,k).
    float wl[4], wr[4];
    int   lt[4], rt[4];
    {
        // numpy computes xp = xmin_ext + k*bin_size as separate fp64 mul+add.
        // hipcc's default -ffp-contract=fast would fuse into one FMA, flipping
        // floor/ceil at exact-integer xp (where the reference weight is 2.0).
        #pragma clang fp contract(off)
        #pragma unroll 4
        for (int c = 0; c < 4; ++c) {
            const int e = t4 * 4 + c;
            const int i = e % T_DIM;
            const int j = (e / T_DIM) % D_PROP;
            const int k = e / (T_DIM * D_PROP);
            wl[c] = 0.0f; wr[c] = 0.0f; lt[c] = 0; rt[c] = 0;
            if (i + j <= T_DIM - 2) {                   // i+j <= 98
                int length = (j + 1) - i;               // can be negative
                double xmin_ext = (double)i - (double)length * 0.5;
                double xmax_ext = (double)(j + 1) + (double)length * 0.5;
                double bin_size = (xmax_ext - xmin_ext) / (double)(N_SMP - 1);
                double kb = (double)k * bin_size;       // separate mul...
                double xp = xmin_ext + kb;              // ...then add (no FMA)
                if (xp >= 0.0 && xp <= (double)(T_DIM - 1)) {
                    double fl = floor(xp);
                    double cl = ceil(xp);
                    lt[c] = (int)fl;
                    rt[c] = (int)cl;
                    wl[c] = (float)(1.0 - (xp - fl));
                    wr[c] = (float)(1.0 - (cl - xp));
                }
            }
        }
    }

    const float* x = xs;
    f4* o = out + (size_t)bc0 * NF4 + t4;
    #pragma unroll 8
    for (int b = 0; b < BC_CHUNK; ++b) {
        f4 v;
        v.x = x[lt[0]] * wl[0] + x[rt[0]] * wr[0];
        v.y = x[lt[1]] * wl[1] + x[rt[1]] * wr[1];
        v.z = x[lt[2]] * wl[2] + x[rt[2]] * wr[2];
        v.w = x[lt[3]] * wl[3] + x[rt[3]] * wr[3];
        if (active)
            __builtin_nontemporal_store(v, o);          // keep writes out of L2
        x += T_DIM;
        o += NF4;
    }
}

extern "C" void kernel_launch(void* const* d_in, const int* in_sizes, int n_in,
                              void* d_out, int out_size, void* d_ws, size_t ws_size,
                              hipStream_t stream) {
    const float* X = (const float*)d_in[0];   // [4,128,100] fp32
    f4* out = (f4*)d_out;                     // [4,128,32,100,100] fp32

    // 80000 float4 per row -> 313 blocks (last block 50% active), 16 bc chunks.
    dim3 grid((NF4 + 255) / 256, BC_TOTAL / BC_CHUNK);
    bms_fused<<<grid, 256, 0, stream>>>(X, out);
}